// Round 1
// baseline (232.084 us; speedup 1.0000x reference)
//
#include <hip/hip_runtime.h>
#include <hip/hip_bf16.h>
#include <math.h>

typedef float f4 __attribute__((ext_vector_type(4)));

#define NG    512   // graphs
#define NPG   64    // nodes per graph
#define EPG   2048  // edges per graph (contiguous by construction)

// ---------------------------------------------------------------------------
// Build dense per-graph L_hat blocks, stored TRANSPOSED:
//   L[g][k][n] = A[n][k], where A[n][k] = sum over edges (row=k,col=n) of
//   -(dinv[row]*ew*dinv[col]).  prop: T1[n][f] = sum_k A[n][k] * T0[k][f].
// ---------------------------------------------------------------------------
__global__ __launch_bounds__(256) void build_L(
    const float* __restrict__ ew, const int* __restrict__ row,
    const int* __restrict__ col, float* __restrict__ L)
{
    __shared__ float sdeg[64];
    __shared__ float sA[64 * 64];  // sA[r*64 + c]
    const int g = blockIdx.x, t = threadIdx.x;

    if (t < 64) sdeg[t] = 0.f;
    for (int i = t; i < 64 * 64; i += 256) sA[i] = 0.f;
    __syncthreads();

    const int e0 = g * EPG;
    for (int e = t; e < EPG; e += 256)
        atomicAdd(&sdeg[row[e0 + e] & 63], ew[e0 + e]);
    __syncthreads();

    if (t < 64) {
        float d = sdeg[t];
        sdeg[t] = (d > 0.f) ? rsqrtf(d) : 0.f;
    }
    __syncthreads();

    for (int e = t; e < EPG; e += 256) {
        const int r = row[e0 + e] & 63;
        const int c = col[e0 + e] & 63;
        const float nw = -(sdeg[r] * ew[e0 + e] * sdeg[c]);
        atomicAdd(&sA[r * 64 + c], nw);   // [k][n] layout == A[n][k] transposed
    }
    __syncthreads();

    for (int i = t; i < 64 * 64; i += 256) L[g * 4096 + i] = sA[i];
}

// ---------------------------------------------------------------------------
// One ChebConv (K=3) layer, one graph per block, 256 threads.
// Threads: tx = t&15 (feature tile), ty = t>>4 (node tile); each thread owns
// a 4x4 register tile.  FIN streamed in 64-wide halves so LDS fits.
// ---------------------------------------------------------------------------
template <int FIN, int FOUT, bool RELU>
__global__ __launch_bounds__(256) void cheb_layer(
    const float* __restrict__ Xin, const float* __restrict__ Lm,
    const float* __restrict__ W, const float* __restrict__ bias,
    float* __restrict__ Xout)
{
    constexpr int NKH = FIN / 64;   // feature halves of the input
    constexpr int NFO = FOUT / 64;  // 64-wide output blocks

    __shared__ float sAT[64][64];   // sAT[k][n] = A[n][k]
    __shared__ float sT0[64][68];   // [node][feat], padded stride 68
    __shared__ float sT1[64][68];
    __shared__ float sT2[64][68];

    const int g = blockIdx.x, t = threadIdx.x;
    const int tx = t & 15, ty = t >> 4;

    for (int i = t; i < 64 * 64; i += 256) (&sAT[0][0])[i] = Lm[g * 4096 + i];

    float out[4][NFO * 4];
#pragma unroll
    for (int i = 0; i < 4; ++i)
#pragma unroll
        for (int j = 0; j < NFO * 4; ++j) out[i][j] = 0.f;

    for (int fh = 0; fh < NKH; ++fh) {
        __syncthreads();  // previous iteration's readers done
        // ---- load X slice: T0[n][f] = Xin[g*64+n][fh*64+f]
        for (int i = t; i < 64 * 64; i += 256) {
            const int n = i >> 6, f = i & 63;
            sT0[n][f] = Xin[(size_t)(g * 64 + n) * FIN + fh * 64 + f];
        }
        __syncthreads();

        // ---- T1 = A @ T0
        {
            float a[4][4] = {};
#pragma unroll 4
            for (int k = 0; k < 64; ++k) {
                const f4 av = *(const f4*)&sAT[k][4 * ty];  // A[4ty+i][k]
                const f4 tv = *(const f4*)&sT0[k][4 * tx];
#pragma unroll
                for (int i = 0; i < 4; ++i)
#pragma unroll
                    for (int j = 0; j < 4; ++j)
                        a[i][j] = fmaf(av[i], tv[j], a[i][j]);
            }
#pragma unroll
            for (int i = 0; i < 4; ++i) {
                f4 r = {a[i][0], a[i][1], a[i][2], a[i][3]};
                *(f4*)&sT1[4 * ty + i][4 * tx] = r;
            }
        }
        __syncthreads();

        // ---- T2 = 2*(A @ T1) - T0
        {
            float a[4][4] = {};
#pragma unroll 4
            for (int k = 0; k < 64; ++k) {
                const f4 av = *(const f4*)&sAT[k][4 * ty];
                const f4 tv = *(const f4*)&sT1[k][4 * tx];
#pragma unroll
                for (int i = 0; i < 4; ++i)
#pragma unroll
                    for (int j = 0; j < 4; ++j)
                        a[i][j] = fmaf(av[i], tv[j], a[i][j]);
            }
#pragma unroll
            for (int i = 0; i < 4; ++i) {
                const f4 t0v = *(const f4*)&sT0[4 * ty + i][4 * tx];
                f4 r;
#pragma unroll
                for (int j = 0; j < 4; ++j) r[j] = 2.f * a[i][j] - t0v[j];
                *(f4*)&sT2[4 * ty + i][4 * tx] = r;
            }
        }
        __syncthreads();

        // ---- out += T0@W0 + T1@W1 + T2@W2 (this feature-half's slice)
#pragma unroll
        for (int t3 = 0; t3 < 3; ++t3) {
            float(*Tt)[68] = (t3 == 0) ? sT0 : (t3 == 1) ? sT1 : sT2;
            const float* Wt = W + ((size_t)t3 * FIN + fh * 64) * FOUT;
#pragma unroll 2
            for (int f = 0; f < 64; ++f) {
                float tv[4];
#pragma unroll
                for (int i = 0; i < 4; ++i) tv[i] = Tt[4 * ty + i][f];
#pragma unroll
                for (int jb = 0; jb < NFO; ++jb) {
                    const f4 wv =
                        *(const f4*)&Wt[(size_t)f * FOUT + jb * 64 + 4 * tx];
#pragma unroll
                    for (int i = 0; i < 4; ++i)
#pragma unroll
                        for (int j = 0; j < 4; ++j)
                            out[i][jb * 4 + j] =
                                fmaf(tv[i], wv[j], out[i][jb * 4 + j]);
                }
            }
        }
    }

    // ---- epilogue: + bias, optional ReLU, store
#pragma unroll
    for (int jb = 0; jb < NFO; ++jb) {
        const f4 bv = *(const f4*)&bias[jb * 64 + 4 * tx];
#pragma unroll
        for (int i = 0; i < 4; ++i) {
            f4 r;
#pragma unroll
            for (int j = 0; j < 4; ++j) {
                float v = out[i][jb * 4 + j] + bv[j];
                if (RELU) v = fmaxf(v, 0.f);
                r[j] = v;
            }
            *(f4*)&Xout[(size_t)(g * 64 + 4 * ty + i) * FOUT + jb * 64 + 4 * tx] = r;
        }
    }
}

// ---------------------------------------------------------------------------
// meanmax readout + FC: out[g][j] = [mean||max] @ fc_w + fc_b
// ---------------------------------------------------------------------------
__global__ __launch_bounds__(256) void readout(
    const float* __restrict__ H,     // N x 64
    const float* __restrict__ fc_w,  // 128 x 64
    const float* __restrict__ fc_b,  // 64
    float* __restrict__ outp)        // G x 64
{
    __shared__ float rm[4][64], rx[4][64];
    __shared__ float smean[64], smax[64];
    const int g = blockIdx.x, t = threadIdx.x;
    const int f = t & 63, q = t >> 6;

    float sum = 0.f, mx = -INFINITY;
    for (int n = q * 16; n < q * 16 + 16; ++n) {
        const float v = H[(size_t)(g * 64 + n) * 64 + f];
        sum += v;
        mx = fmaxf(mx, v);
    }
    rm[q][f] = sum;
    rx[q][f] = mx;
    __syncthreads();

    if (t < 64) {
        smean[t] = (rm[0][t] + rm[1][t] + rm[2][t] + rm[3][t]) * (1.f / 64.f);
        smax[t] = fmaxf(fmaxf(rx[0][t], rx[1][t]), fmaxf(rx[2][t], rx[3][t]));
    }
    __syncthreads();

    if (t < 64) {
        float acc = fc_b[t];
        for (int f2 = 0; f2 < 64; ++f2)
            acc += smean[f2] * fc_w[f2 * 64 + t] + smax[f2] * fc_w[(64 + f2) * 64 + t];
        outp[(size_t)g * 64 + t] = acc;
    }
}

// ---------------------------------------------------------------------------
extern "C" void kernel_launch(void* const* d_in, const int* in_sizes, int n_in,
                              void* d_out, int out_size, void* d_ws, size_t ws_size,
                              hipStream_t stream)
{
    const float* x    = (const float*)d_in[0];   // 32768 x 64
    const float* ew   = (const float*)d_in[1];   // 1048576
    const float* W1   = (const float*)d_in[2];   // 3 x 64 x 128
    const float* b1   = (const float*)d_in[3];   // 128
    const float* W2   = (const float*)d_in[4];   // 3 x 128 x 128
    const float* b2   = (const float*)d_in[5];   // 128
    const float* W3   = (const float*)d_in[6];   // 3 x 128 x 64
    const float* b3   = (const float*)d_in[7];   // 64
    const float* fcw  = (const float*)d_in[8];   // 128 x 64
    const float* fcb  = (const float*)d_in[9];   // 64
    const int*   row  = (const int*)d_in[10];    // 1048576
    const int*   col  = (const int*)d_in[11];    // 1048576
    // d_in[12] = batch (unused: graph membership is n/64 by construction)

    float* Lw = (float*)d_ws;                    // 512*4096 floats   (8 MB)
    float* h1 = Lw + (size_t)NG * 4096;          // 32768*128 floats (16 MB)
    float* h2 = h1 + (size_t)32768 * 128;        // 32768*128 floats (16 MB)
    float* h3 = h1;                              // reuse h1 (dead after layer 2)

    build_L<<<NG, 256, 0, stream>>>(ew, row, col, Lw);
    cheb_layer<64, 128, true><<<NG, 256, 0, stream>>>(x, Lw, W1, b1, h1);
    cheb_layer<128, 128, true><<<NG, 256, 0, stream>>>(h1, Lw, W2, b2, h2);
    cheb_layer<128, 64, false><<<NG, 256, 0, stream>>>(h2, Lw, W3, b3, h3);
    readout<<<NG, 256, 0, stream>>>(h3, fcw, fcb, (float*)d_out);
}

// Round 2
// 57.040 us; speedup vs baseline: 4.0688x; 4.0688x over previous
//
#include <hip/hip_runtime.h>
#include <hip/hip_bf16.h>
#include <math.h>

typedef float  f32x4  __attribute__((ext_vector_type(4)));
typedef short  bf16x8 __attribute__((ext_vector_type(8)));

#define NG  512
#define EPG 2048

__device__ __forceinline__ unsigned short f2bf(float f) {
    union { float f; unsigned u; } v; v.f = f;
    unsigned r = v.u + 0x7fffu + ((v.u >> 16) & 1u);   // RNE
    return (unsigned short)(r >> 16);
}
__device__ __forceinline__ float bf2f(unsigned short h) {
    union { unsigned u; float f; } v; v.u = ((unsigned)h) << 16;
    return v.f;
}
__device__ __forceinline__ bf16x8 ubf(uint4 u) {
    union { uint4 a; bf16x8 b; } c; c.a = u; return c.b;
}

// ---------------------------------------------------------------------------
// build_L: dense 64x64 L_hat per graph, packed into MFMA B-operand fragments
// of L^T for the transposed prop  T~1 = T~0 @ L^T.
// frag(kt,nt), slot(lane,j) = L[nt*16+li][kt*32+lg*8+j] = sA[(k)*64 + n]
// (sA[r*64+c] accumulates edge (row=r,col=c): L[c][r] += nw  => L[n][k]=sA[k*64+n])
// ---------------------------------------------------------------------------
__global__ __launch_bounds__(256) void build_L(
    const float* __restrict__ ew, const int* __restrict__ row,
    const int* __restrict__ col, uint4* __restrict__ Ap)
{
    __shared__ float sdeg[64];
    __shared__ float sA[64 * 64];
    const int g = blockIdx.x, t = threadIdx.x;

    if (t < 64) sdeg[t] = 0.f;
    for (int i = t; i < 4096; i += 256) sA[i] = 0.f;
    __syncthreads();

    const int e0 = g * EPG;
    for (int e = t; e < EPG; e += 256) atomicAdd(&sdeg[row[e0+e] & 63], ew[e0+e]);
    __syncthreads();
    if (t < 64) { float d = sdeg[t]; sdeg[t] = (d > 0.f) ? rsqrtf(d) : 0.f; }
    __syncthreads();
    for (int e = t; e < EPG; e += 256) {
        int r = row[e0+e] & 63, c = col[e0+e] & 63;
        atomicAdd(&sA[r*64 + c], -(sdeg[r] * ew[e0+e] * sdeg[c]));
    }
    __syncthreads();

    for (int idx = t; idx < 512; idx += 256) {
        int frag = idx >> 6, lane = idx & 63;
        int kt = frag >> 2, nt = frag & 3;
        int lg = lane >> 4, li = lane & 15;
        int k0 = kt*32 + lg*8, n = nt*16 + li;
        unsigned v[4];
#pragma unroll
        for (int jp = 0; jp < 4; ++jp) {
            unsigned lo = f2bf(sA[(k0 + 2*jp    )*64 + n]);
            unsigned hi = f2bf(sA[(k0 + 2*jp + 1)*64 + n]);
            v[jp] = lo | (hi << 16);
        }
        Ap[(size_t)g*512 + (size_t)frag*64 + lane] = make_uint4(v[0],v[1],v[2],v[3]);
    }
}

// ---------------------------------------------------------------------------
// wpack: W[t3][fin][fout] f32 -> bf16 MFMA B-fragments.
// frag(t3,kt,nt), slot(lane,j) = W[t3][kt*32+lg*8+j][nt*16+li]
// layout: [layer][t3][ktG][nt][lane]; layer offsets 0 / 48 / 144 frags.
// ---------------------------------------------------------------------------
__global__ __launch_bounds__(64) void wpack(
    const float* __restrict__ W1, const float* __restrict__ W2,
    const float* __restrict__ W3, uint4* __restrict__ Wp)
{
    int b = blockIdx.x, lane = threadIdx.x;
    const float* W; int FIN, FOUT, rel, off;
    if (b < 48)       { W = W1; FIN = 64;  FOUT = 128; rel = b;       off = 0;   }
    else if (b < 144) { W = W2; FIN = 128; FOUT = 128; rel = b - 48;  off = 48;  }
    else              { W = W3; FIN = 128; FOUT = 64;  rel = b - 144; off = 144; }
    int NKT = FIN / 32, NNT = FOUT / 16;
    int t3 = rel / (NKT * NNT), r2 = rel % (NKT * NNT);
    int kt = r2 / NNT, nt = r2 % NNT;
    int lg = lane >> 4, li = lane & 15;
    int fin0 = kt*32 + lg*8, fout = nt*16 + li;
    unsigned v[4];
#pragma unroll
    for (int jp = 0; jp < 4; ++jp) {
        unsigned lo = f2bf(W[((size_t)t3*FIN + fin0 + 2*jp    ) * FOUT + fout]);
        unsigned hi = f2bf(W[((size_t)t3*FIN + fin0 + 2*jp + 1) * FOUT + fout]);
        v[jp] = lo | (hi << 16);
    }
    Wp[(size_t)(off + rel)*64 + lane] = make_uint4(v[0],v[1],v[2],v[3]);
}

// ---------------------------------------------------------------------------
// cheb_mfma: one ChebConv layer (K=3), one graph / block, 4 waves.
// LDS tiles: 64x64 bf16, row stride 128B, XOR swizzle byte^=((row&7)<<4).
//   Tf* : feature-major T~[f][node]  (prop A-operand, ds_read_b128)
//   Tn* : node-major    T[node][f]   (weight A-operand, ds_read_b128)
// prop (transposed): T~1 = T~0 @ L^T  -> C: col=node(li), row=feat(lg*4+r)
//   => node-major write = ds_write_b64; feat-major copy = 4x ds_write_b16.
// weight: out = sum_t3 T_t3 @ W_t3    -> C: col=fout(li), row=node(lg*4+r)
// ---------------------------------------------------------------------------
template <int FIN, int FOUT, bool RELU, bool L1, bool WT>
__global__ __launch_bounds__(256) void cheb_mfma(
    const unsigned short* __restrict__ Hin,   // [N][FIN] bf16 (unused if L1)
    const unsigned short* __restrict__ Htin,  // [G][FIN][64] bf16 (unused if L1)
    const float* __restrict__ Xf32,           // [N][64] f32 (L1 only)
    const uint4* __restrict__ Ap,
    const uint4* __restrict__ Wp,             // this layer's fragment base
    const float* __restrict__ bias,
    unsigned short* __restrict__ Hout,        // [N][FOUT] bf16
    unsigned short* __restrict__ Htout)       // [G][FOUT][64] bf16 (if WT)
{
    constexpr int NCH = FIN / 64;
    constexpr int NTO = FOUT / 64;   // fout 16-tiles per wave (128->2, 64->1)
    constexpr int NKT = FIN / 32;
    constexpr int NNT = FOUT / 16;

    __shared__ __align__(16) unsigned short Tf0[4096];
    __shared__ __align__(16) unsigned short Tn0[4096];
    __shared__ __align__(16) unsigned short Tf1[4096];
    __shared__ __align__(16) unsigned short Tn1[4096];
    __shared__ __align__(16) unsigned short Tn2[4096];

    const int g = blockIdx.x, t = threadIdx.x;
    const int w = t >> 6, lane = t & 63, lg = lane >> 4, li = lane & 15;
    const int mt = w;                 // wave's feat row-tile for props

    uint4 afr[2][4];
    {
        const uint4* Ag = Ap + (size_t)g * 512;
#pragma unroll
        for (int kt = 0; kt < 2; ++kt)
#pragma unroll
            for (int nt = 0; nt < 4; ++nt)
                afr[kt][nt] = Ag[(kt*4 + nt)*64 + lane];
    }

    f32x4 oacc[4][NTO];
#pragma unroll
    for (int m2 = 0; m2 < 4; ++m2)
#pragma unroll
        for (int no = 0; no < NTO; ++no) oacc[m2][no] = (f32x4){0.f,0.f,0.f,0.f};

    for (int ch = 0; ch < NCH; ++ch) {
        // ---------------- stage Tf0 / Tn0
        if (L1) {
            const float4* xg = (const float4*)(Xf32 + (size_t)g*4096);
            for (int i = t; i < 1024; i += 256) {
                int node = i >> 4, q = i & 15, f0 = q*4;
                float4 v = xg[i];
                unsigned short h0 = f2bf(v.x), h1 = f2bf(v.y);
                unsigned short h2 = f2bf(v.z), h3 = f2bf(v.w);
                *(uint2*)((char*)Tn0 + node*128 + ((f0*2) ^ ((node&7)<<4))) =
                    make_uint2(h0 | ((unsigned)h1<<16), h2 | ((unsigned)h3<<16));
                *(unsigned short*)((char*)Tf0 + (f0+0)*128 + ((node*2) ^ (((f0+0)&7)<<4))) = h0;
                *(unsigned short*)((char*)Tf0 + (f0+1)*128 + ((node*2) ^ (((f0+1)&7)<<4))) = h1;
                *(unsigned short*)((char*)Tf0 + (f0+2)*128 + ((node*2) ^ (((f0+2)&7)<<4))) = h2;
                *(unsigned short*)((char*)Tf0 + (f0+3)*128 + ((node*2) ^ (((f0+3)&7)<<4))) = h3;
            }
        } else {
            const char* srcT = (const char*)(Htin + (size_t)g*FIN*64 + (size_t)ch*4096);
            const char* srcN = (const char*)(Hin  + (size_t)g*64*FIN + ch*64);
            for (int i = t; i < 512; i += 256) {
                int p = i * 16, r = p >> 7, gr = (p & 127) >> 4;
                int sg = (gr ^ (r & 7)) * 16;
                *(uint4*)((char*)Tf0 + p) = *(const uint4*)(srcT + r*128      + sg);
                *(uint4*)((char*)Tn0 + p) = *(const uint4*)(srcN + r*(FIN*2) + sg);
            }
        }
        __syncthreads();

        const int arow = mt*16 + li;
        const int nswz = (arow & 7) << 4;

        // ---------------- prop1: T~1 = T~0 @ L^T
        {
            bf16x8 a0[2];
#pragma unroll
            for (int kt = 0; kt < 2; ++kt)
                a0[kt] = *(const bf16x8*)((const char*)Tf0 + arow*128 + ((kt*64 + lg*16) ^ nswz));
#pragma unroll
            for (int nt = 0; nt < 4; ++nt) {
                f32x4 p = {0.f,0.f,0.f,0.f};
                p = __builtin_amdgcn_mfma_f32_16x16x32_bf16(a0[0], ubf(afr[0][nt]), p, 0,0,0);
                p = __builtin_amdgcn_mfma_f32_16x16x32_bf16(a0[1], ubf(afr[1][nt]), p, 0,0,0);
                unsigned short q0 = f2bf(p[0]), q1 = f2bf(p[1]);
                unsigned short q2 = f2bf(p[2]), q3 = f2bf(p[3]);
                int nrow = nt*16 + li, fcol = mt*16 + lg*4;
                *(uint2*)((char*)Tn1 + nrow*128 + ((fcol*2) ^ ((nrow&7)<<4))) =
                    make_uint2(q0 | ((unsigned)q1<<16), q2 | ((unsigned)q3<<16));
                *(unsigned short*)((char*)Tf1 + (fcol+0)*128 + ((nrow*2) ^ (((fcol+0)&7)<<4))) = q0;
                *(unsigned short*)((char*)Tf1 + (fcol+1)*128 + ((nrow*2) ^ (((fcol+1)&7)<<4))) = q1;
                *(unsigned short*)((char*)Tf1 + (fcol+2)*128 + ((nrow*2) ^ (((fcol+2)&7)<<4))) = q2;
                *(unsigned short*)((char*)Tf1 + (fcol+3)*128 + ((nrow*2) ^ (((fcol+3)&7)<<4))) = q3;
            }
        }
        // ---------------- prop2: T2 = 2*L@T1 - T0   (same-wave rows: no barrier)
        {
            bf16x8 a1[2];
#pragma unroll
            for (int kt = 0; kt < 2; ++kt)
                a1[kt] = *(const bf16x8*)((const char*)Tf1 + arow*128 + ((kt*64 + lg*16) ^ nswz));
#pragma unroll
            for (int nt = 0; nt < 4; ++nt) {
                f32x4 p = {0.f,0.f,0.f,0.f};
                p = __builtin_amdgcn_mfma_f32_16x16x32_bf16(a1[0], ubf(afr[0][nt]), p, 0,0,0);
                p = __builtin_amdgcn_mfma_f32_16x16x32_bf16(a1[1], ubf(afr[1][nt]), p, 0,0,0);
                int nrow = nt*16 + li, fcol = mt*16 + lg*4;
                uint2 t0p = *(const uint2*)((const char*)Tn0 + nrow*128 + ((fcol*2) ^ ((nrow&7)<<4)));
                float t00 = bf2f((unsigned short)(t0p.x & 0xffff));
                float t01 = bf2f((unsigned short)(t0p.x >> 16));
                float t02 = bf2f((unsigned short)(t0p.y & 0xffff));
                float t03 = bf2f((unsigned short)(t0p.y >> 16));
                unsigned short q0 = f2bf(2.f*p[0] - t00), q1 = f2bf(2.f*p[1] - t01);
                unsigned short q2 = f2bf(2.f*p[2] - t02), q3 = f2bf(2.f*p[3] - t03);
                *(uint2*)((char*)Tn2 + nrow*128 + ((fcol*2) ^ ((nrow&7)<<4))) =
                    make_uint2(q0 | ((unsigned)q1<<16), q2 | ((unsigned)q3<<16));
            }
        }
        __syncthreads();

        // ---------------- weight MFMAs: out += T_t3 @ W_t3 (this chunk's K)
#pragma unroll
        for (int t3 = 0; t3 < 3; ++t3) {
            const unsigned short* Ts = (t3==0) ? Tn0 : (t3==1) ? Tn1 : Tn2;
#pragma unroll
            for (int kt = 0; kt < 2; ++kt) {
                int ktG = ch*2 + kt;
                bf16x8 ta[4];
#pragma unroll
                for (int m2 = 0; m2 < 4; ++m2) {
                    int rr = m2*16 + li;
                    ta[m2] = *(const bf16x8*)((const char*)Ts + rr*128 + ((kt*64 + lg*16) ^ ((rr&7)<<4)));
                }
#pragma unroll
                for (int no = 0; no < NTO; ++no) {
                    int ntg = w*NTO + no;
                    bf16x8 wf = ubf(Wp[((size_t)(t3*NKT + ktG)*NNT + ntg)*64 + lane]);
#pragma unroll
                    for (int m2 = 0; m2 < 4; ++m2)
                        oacc[m2][no] = __builtin_amdgcn_mfma_f32_16x16x32_bf16(ta[m2], wf, oacc[m2][no], 0,0,0);
                }
            }
        }
        __syncthreads();
    }

    // ---------------- epilogue: bias (+ReLU), dual global store
#pragma unroll
    for (int no = 0; no < NTO; ++no) {
        int fout = (w*NTO + no)*16 + li;
        float bv = bias[fout];
#pragma unroll
        for (int m2 = 0; m2 < 4; ++m2) {
            f32x4 v = oacc[m2][no];
            unsigned short q[4];
#pragma unroll
            for (int r = 0; r < 4; ++r) {
                float o = v[r] + bv;
                if (RELU) o = fmaxf(o, 0.f);
                q[r] = f2bf(o);
            }
            int node0 = g*64 + m2*16 + lg*4;
#pragma unroll
            for (int r = 0; r < 4; ++r)
                Hout[(size_t)(node0 + r)*FOUT + fout] = q[r];
            if (WT)
                *(uint2*)(Htout + (size_t)g*FOUT*64 + (size_t)fout*64 + m2*16 + lg*4) =
                    make_uint2(q[0] | ((unsigned)q[1]<<16), q[2] | ((unsigned)q[3]<<16));
        }
    }
}

// ---------------------------------------------------------------------------
// meanmax readout + FC (bf16 input, f32 math)
// ---------------------------------------------------------------------------
__global__ __launch_bounds__(256) void readout(
    const unsigned short* __restrict__ H,  // [N][64] bf16
    const float* __restrict__ fc_w, const float* __restrict__ fc_b,
    float* __restrict__ outp)
{
    __shared__ float rm[4][64], rx[4][64];
    __shared__ float smean[64], smax[64];
    const int g = blockIdx.x, t = threadIdx.x;
    const int f = t & 63, q = t >> 6;

    float sum = 0.f, mx = -INFINITY;
    for (int n = q * 16; n < q * 16 + 16; ++n) {
        float v = bf2f(H[(size_t)(g*64 + n)*64 + f]);
        sum += v; mx = fmaxf(mx, v);
    }
    rm[q][f] = sum; rx[q][f] = mx;
    __syncthreads();

    if (t < 64) {
        smean[t] = (rm[0][t] + rm[1][t] + rm[2][t] + rm[3][t]) * (1.f/64.f);
        smax[t]  = fmaxf(fmaxf(rx[0][t], rx[1][t]), fmaxf(rx[2][t], rx[3][t]));
    }
    __syncthreads();

    if (t < 64) {
        float acc = fc_b[t];
        for (int f2 = 0; f2 < 64; ++f2)
            acc += smean[f2]*fc_w[f2*64 + t] + smax[f2]*fc_w[(64 + f2)*64 + t];
        outp[(size_t)g*64 + t] = acc;
    }
}

// ---------------------------------------------------------------------------
extern "C" void kernel_launch(void* const* d_in, const int* in_sizes, int n_in,
                              void* d_out, int out_size, void* d_ws, size_t ws_size,
                              hipStream_t stream)
{
    const float* x   = (const float*)d_in[0];
    const float* ew  = (const float*)d_in[1];
    const float* W1  = (const float*)d_in[2];
    const float* b1  = (const float*)d_in[3];
    const float* W2  = (const float*)d_in[4];
    const float* b2  = (const float*)d_in[5];
    const float* W3  = (const float*)d_in[6];
    const float* b3  = (const float*)d_in[7];
    const float* fcw = (const float*)d_in[8];
    const float* fcb = (const float*)d_in[9];
    const int*   row = (const int*)d_in[10];
    const int*   col = (const int*)d_in[11];

    char* ws = (char*)d_ws;
    uint4* Ap = (uint4*)ws;                         ws += (size_t)NG*512*16;      // 4MB
    uint4* Wp = (uint4*)ws;                         ws += (size_t)192*64*16;      // 192KB
    unsigned short* h1  = (unsigned short*)ws;      ws += (size_t)32768*128*2;    // 8MB
    unsigned short* ht1 = (unsigned short*)ws;      ws += (size_t)NG*128*64*2;    // 8MB
    unsigned short* h2  = (unsigned short*)ws;      ws += (size_t)32768*128*2;    // 8MB
    unsigned short* ht2 = (unsigned short*)ws;      ws += (size_t)NG*128*64*2;    // 8MB
    unsigned short* h3  = (unsigned short*)ws;      ws += (size_t)32768*64*2;     // 4MB

    build_L<<<NG, 256, 0, stream>>>(ew, row, col, Ap);
    wpack<<<192, 64, 0, stream>>>(W1, W2, W3, Wp);

    cheb_mfma<64, 128, true, true, true><<<NG, 256, 0, stream>>>(
        nullptr, nullptr, x, Ap, Wp, b1, h1, ht1);
    cheb_mfma<128, 128, true, false, true><<<NG, 256, 0, stream>>>(
        h1, ht1, nullptr, Ap, Wp + (size_t)48*64, b2, h2, ht2);
    cheb_mfma<128, 64, false, false, false><<<NG, 256, 0, stream>>>(
        h2, ht2, nullptr, Ap, Wp + (size_t)144*64, b3, h3, nullptr);

    readout<<<NG, 256, 0, stream>>>(h3, fcw, fcb, (float*)d_out);
}

// Round 3
// 46.048 us; speedup vs baseline: 5.0401x; 1.2387x over previous
//
#include <hip/hip_runtime.h>
#include <math.h>

typedef float  f32x4  __attribute__((ext_vector_type(4)));
typedef short  bf16x8 __attribute__((ext_vector_type(8)));

#define NG  512
#define EPG 2048

__device__ __forceinline__ unsigned short f2bf(float f) {
    union { float f; unsigned u; } v; v.f = f;
    unsigned r = v.u + 0x7fffu + ((v.u >> 16) & 1u);   // RNE
    return (unsigned short)(r >> 16);
}
__device__ __forceinline__ float bf2f(unsigned short h) {
    union { unsigned u; float f; } v; v.u = ((unsigned)h) << 16;
    return v.f;
}
__device__ __forceinline__ bf16x8 ubf(uint4 u) {
    union { uint4 a; bf16x8 b; } c; c.a = u; return c.b;
}

// ---------------------------------------------------------------------------
// wpack: W[t3][fin][fout] f32 -> bf16 MFMA B-fragments (verified round 2).
// frag(t3,kt,nt), slot(lane,j) = W[t3][kt*32+lg*8+j][nt*16+li]
// ---------------------------------------------------------------------------
__global__ __launch_bounds__(64) void wpack(
    const float* __restrict__ W1, const float* __restrict__ W2,
    const float* __restrict__ W3, uint4* __restrict__ Wp)
{
    int b = blockIdx.x, lane = threadIdx.x;
    const float* W; int FIN, FOUT, rel, off;
    if (b < 48)       { W = W1; FIN = 64;  FOUT = 128; rel = b;       off = 0;   }
    else if (b < 144) { W = W2; FIN = 128; FOUT = 128; rel = b - 48;  off = 48;  }
    else              { W = W3; FIN = 128; FOUT = 64;  rel = b - 144; off = 144; }
    int NKT = FIN / 32, NNT = FOUT / 16;
    int t3 = rel / (NKT * NNT), r2 = rel % (NKT * NNT);
    int kt = r2 / NNT, nt = r2 % NNT;
    int lg = lane >> 4, li = lane & 15;
    int fin0 = kt*32 + lg*8, fout = nt*16 + li;
    unsigned v[4];
#pragma unroll
    for (int jp = 0; jp < 4; ++jp) {
        unsigned lo = f2bf(W[((size_t)t3*FIN + fin0 + 2*jp    ) * FOUT + fout]);
        unsigned hi = f2bf(W[((size_t)t3*FIN + fin0 + 2*jp + 1) * FOUT + fout]);
        v[jp] = lo | (hi << 16);
    }
    Wp[(size_t)(off + rel)*64 + lane] = make_uint4(v[0],v[1],v[2],v[3]);
}

// ---------------------------------------------------------------------------
// One ChebConv layer entirely in LDS.
//   H  : node-major [64][128] bf16, row stride 256B, swz: byte^=((node&7)<<4)
//   Ht : feat-major [128][64] bf16, row stride 128B, swz: byte^=((feat&7)<<4)
//   Tf1/Tn1/Tn2 : chunk-local 64x64 scratch tiles, stride 128B, same swz
// prop (transposed): T~1 = T~0 @ L^T; weight: out += sum_t3 T_t3 @ W_t3.
// ---------------------------------------------------------------------------
template <int FIN, int FOUT, bool RELU, bool WT>
__device__ __forceinline__ void layer(
    unsigned short* H, unsigned short* Ht,
    unsigned short* Tf1, unsigned short* Tn1, unsigned short* Tn2,
    const uint4 (&afr)[2][4], const uint4* __restrict__ Wp,
    const float* __restrict__ bias,
    int w, int lg, int li, int lane)
{
    constexpr int NCH = FIN / 64;
    constexpr int NTO = FOUT / 64;
    constexpr int NKT = FIN / 32;
    constexpr int NNT = FOUT / 16;

    f32x4 oacc[4][NTO];
#pragma unroll
    for (int m2 = 0; m2 < 4; ++m2)
#pragma unroll
        for (int no = 0; no < NTO; ++no) oacc[m2][no] = (f32x4){0.f,0.f,0.f,0.f};

    for (int ch = 0; ch < NCH; ++ch) {
        if (ch) __syncthreads();   // scratch tiles free again

        // prefetch this chunk's W fragments (L2-resident)
        uint4 wfr[3][2][NTO];
#pragma unroll
        for (int t3 = 0; t3 < 3; ++t3)
#pragma unroll
            for (int kt = 0; kt < 2; ++kt)
#pragma unroll
                for (int no = 0; no < NTO; ++no)
                    wfr[t3][kt][no] =
                        Wp[((size_t)(t3*NKT + ch*2 + kt)*NNT + w*NTO + no)*64 + lane];

        const int fcol = w*16 + lg*4;          // chunk-local feat col of prop C
        // ---------------- prop1: T~1 = T~0 @ L^T  (A from Ht)
        {
            const int frow = ch*64 + w*16 + li;
            const int fsw  = (frow & 7) << 4;
            bf16x8 a0[2];
#pragma unroll
            for (int kt = 0; kt < 2; ++kt)
                a0[kt] = *(const bf16x8*)((const char*)Ht + frow*128 + ((kt*64 + lg*16) ^ fsw));
#pragma unroll
            for (int nt = 0; nt < 4; ++nt) {
                f32x4 p = {0.f,0.f,0.f,0.f};
                p = __builtin_amdgcn_mfma_f32_16x16x32_bf16(a0[0], ubf(afr[0][nt]), p, 0,0,0);
                p = __builtin_amdgcn_mfma_f32_16x16x32_bf16(a0[1], ubf(afr[1][nt]), p, 0,0,0);
                unsigned short q0 = f2bf(p[0]), q1 = f2bf(p[1]);
                unsigned short q2 = f2bf(p[2]), q3 = f2bf(p[3]);
                const int nrow = nt*16 + li;
                *(uint2*)((char*)Tn1 + nrow*128 + ((fcol*2) ^ ((nrow&7)<<4))) =
                    make_uint2(q0 | ((unsigned)q1<<16), q2 | ((unsigned)q3<<16));
                *(unsigned short*)((char*)Tf1 + (fcol+0)*128 + ((nrow*2) ^ (((fcol+0)&7)<<4))) = q0;
                *(unsigned short*)((char*)Tf1 + (fcol+1)*128 + ((nrow*2) ^ (((fcol+1)&7)<<4))) = q1;
                *(unsigned short*)((char*)Tf1 + (fcol+2)*128 + ((nrow*2) ^ (((fcol+2)&7)<<4))) = q2;
                *(unsigned short*)((char*)Tf1 + (fcol+3)*128 + ((nrow*2) ^ (((fcol+3)&7)<<4))) = q3;
            }
        }
        // ---------------- prop2: T2 = 2*(T~1 @ L^T) - T0 (same-wave rows)
        {
            const int frow = w*16 + li;
            const int fsw  = (frow & 7) << 4;
            bf16x8 a1[2];
#pragma unroll
            for (int kt = 0; kt < 2; ++kt)
                a1[kt] = *(const bf16x8*)((const char*)Tf1 + frow*128 + ((kt*64 + lg*16) ^ fsw));
#pragma unroll
            for (int nt = 0; nt < 4; ++nt) {
                f32x4 p = {0.f,0.f,0.f,0.f};
                p = __builtin_amdgcn_mfma_f32_16x16x32_bf16(a1[0], ubf(afr[0][nt]), p, 0,0,0);
                p = __builtin_amdgcn_mfma_f32_16x16x32_bf16(a1[1], ubf(afr[1][nt]), p, 0,0,0);
                const int nrow = nt*16 + li;
                uint2 t0p = *(const uint2*)((const char*)H + nrow*256 +
                                            (((ch*64 + fcol)*2) ^ ((nrow&7)<<4)));
                float t00 = bf2f((unsigned short)(t0p.x & 0xffff));
                float t01 = bf2f((unsigned short)(t0p.x >> 16));
                float t02 = bf2f((unsigned short)(t0p.y & 0xffff));
                float t03 = bf2f((unsigned short)(t0p.y >> 16));
                unsigned short q0 = f2bf(2.f*p[0] - t00), q1 = f2bf(2.f*p[1] - t01);
                unsigned short q2 = f2bf(2.f*p[2] - t02), q3 = f2bf(2.f*p[3] - t03);
                *(uint2*)((char*)Tn2 + nrow*128 + ((fcol*2) ^ ((nrow&7)<<4))) =
                    make_uint2(q0 | ((unsigned)q1<<16), q2 | ((unsigned)q3<<16));
            }
        }
        __syncthreads();

        // ---------------- weight MFMAs: out += T_t3 @ W_t3
#pragma unroll
        for (int t3 = 0; t3 < 3; ++t3) {
#pragma unroll
            for (int kt = 0; kt < 2; ++kt) {
                bf16x8 ta[4];
#pragma unroll
                for (int m2 = 0; m2 < 4; ++m2) {
                    const int rr = m2*16 + li;
                    const int sw = (rr & 7) << 4;
                    if (t3 == 0)
                        ta[m2] = *(const bf16x8*)((const char*)H + rr*256 +
                                                  ((ch*128 + kt*64 + lg*16) ^ sw));
                    else {
                        const unsigned short* Ts = (t3 == 1) ? Tn1 : Tn2;
                        ta[m2] = *(const bf16x8*)((const char*)Ts + rr*128 +
                                                  ((kt*64 + lg*16) ^ sw));
                    }
                }
#pragma unroll
                for (int no = 0; no < NTO; ++no)
#pragma unroll
                    for (int m2 = 0; m2 < 4; ++m2)
                        oacc[m2][no] = __builtin_amdgcn_mfma_f32_16x16x32_bf16(
                            ta[m2], ubf(wfr[t3][kt][no]), oacc[m2][no], 0,0,0);
            }
        }
    }
    __syncthreads();   // all reads of H/Ht (input) done -> safe to overwrite

    // ---------------- epilogue: bias (+ReLU), write H (+Ht) in LDS
#pragma unroll
    for (int no = 0; no < NTO; ++no) {
        const int fout = (w*NTO + no)*16 + li;
        const float bv = bias[fout];
#pragma unroll
        for (int m2 = 0; m2 < 4; ++m2) {
            f32x4 v = oacc[m2][no];
            unsigned short q[4];
#pragma unroll
            for (int r = 0; r < 4; ++r) {
                float o = v[r] + bv;
                if (RELU) o = fmaxf(o, 0.f);
                q[r] = f2bf(o);
            }
            const int node0 = m2*16 + lg*4;
#pragma unroll
            for (int r = 0; r < 4; ++r)
                *(unsigned short*)((char*)H + (node0+r)*256 +
                                   ((fout*2) ^ (((node0+r)&7)<<4))) = q[r];
            if (WT)
                *(uint2*)((char*)Ht + fout*128 + ((node0*2) ^ ((fout&7)<<4))) =
                    make_uint2(q[0] | ((unsigned)q[1]<<16), q[2] | ((unsigned)q[3]<<16));
        }
    }
}

// ---------------------------------------------------------------------------
// fused: build L_hat -> 3 ChebConv layers -> meanmax readout + FC, one block
// per graph, everything in LDS.
// ---------------------------------------------------------------------------
__global__ __launch_bounds__(256) void fused(
    const float* __restrict__ X,  const float* __restrict__ ew,
    const int* __restrict__ row,  const int* __restrict__ col,
    const uint4* __restrict__ Wp,
    const float* __restrict__ b1, const float* __restrict__ b2,
    const float* __restrict__ b3,
    const float* __restrict__ fcw, const float* __restrict__ fcb,
    float* __restrict__ outp)
{
    __shared__ __align__(16) char smem[57344];
    unsigned short* H   = (unsigned short*)smem;            // 16KB
    unsigned short* Ht  = (unsigned short*)(smem + 16384);  // 16KB
    unsigned short* Tf1 = (unsigned short*)(smem + 32768);  // 8KB
    unsigned short* Tn1 = (unsigned short*)(smem + 40960);  // 8KB
    unsigned short* Tn2 = (unsigned short*)(smem + 49152);  // 8KB
    float* sA   = (float*)(smem + 32768);                   // 16KB alias Tf1+Tn1
    float* sdeg = (float*)(smem + 49152);                   // alias Tn2

    const int g = blockIdx.x, t = threadIdx.x;
    const int w = t >> 6, lane = t & 63, lg = lane >> 4, li = lane & 15;

    // ---- phase 0: dense L_hat in sA  (sA[r*64+c] = L[c][r], i.e. transposed)
    for (int i = t; i < 4096; i += 256) sA[i] = 0.f;
    if (t < 64) sdeg[t] = 0.f;
    __syncthreads();
    const int e0 = g * EPG;
    for (int e = t; e < EPG; e += 256) atomicAdd(&sdeg[row[e0+e] & 63], ew[e0+e]);
    __syncthreads();
    if (t < 64) { float d = sdeg[t]; sdeg[t] = (d > 0.f) ? rsqrtf(d) : 0.f; }
    __syncthreads();
    for (int e = t; e < EPG; e += 256) {
        int r = row[e0+e] & 63, c = col[e0+e] & 63;
        atomicAdd(&sA[r*64 + c], -(sdeg[r] * ew[e0+e] * sdeg[c]));
    }
    __syncthreads();

    // ---- pack L^T B-fragments into registers (each wave keeps all 8)
    uint4 afr[2][4];
#pragma unroll
    for (int kt = 0; kt < 2; ++kt)
#pragma unroll
        for (int nt = 0; nt < 4; ++nt) {
            const int k0 = kt*32 + lg*8, n = nt*16 + li;
            unsigned v[4];
#pragma unroll
            for (int jp = 0; jp < 4; ++jp) {
                unsigned lo = f2bf(sA[(k0 + 2*jp    )*64 + n]);
                unsigned hi = f2bf(sA[(k0 + 2*jp + 1)*64 + n]);
                v[jp] = lo | (hi << 16);
            }
            afr[kt][nt] = make_uint4(v[0], v[1], v[2], v[3]);
        }

    // ---- stage x (f32 global) into H / Ht as bf16
    const float4* xg = (const float4*)(X + (size_t)g * 4096);
    for (int i = t; i < 1024; i += 256) {
        const int node = i >> 4, f0 = (i & 15) * 4;
        float4 v = xg[i];
        unsigned short h0 = f2bf(v.x), h1 = f2bf(v.y);
        unsigned short h2 = f2bf(v.z), h3 = f2bf(v.w);
        *(uint2*)((char*)H + node*256 + ((f0*2) ^ ((node&7)<<4))) =
            make_uint2(h0 | ((unsigned)h1<<16), h2 | ((unsigned)h3<<16));
        *(unsigned short*)((char*)Ht + (f0+0)*128 + ((node*2) ^ (((f0+0)&7)<<4))) = h0;
        *(unsigned short*)((char*)Ht + (f0+1)*128 + ((node*2) ^ (((f0+1)&7)<<4))) = h1;
        *(unsigned short*)((char*)Ht + (f0+2)*128 + ((node*2) ^ (((f0+2)&7)<<4))) = h2;
        *(unsigned short*)((char*)Ht + (f0+3)*128 + ((node*2) ^ (((f0+3)&7)<<4))) = h3;
    }
    __syncthreads();   // sA reads + x staging complete

    layer<64, 128, true,  true >(H, Ht, Tf1, Tn1, Tn2, afr, Wp,                    b1, w, lg, li, lane);
    __syncthreads();
    layer<128, 128, true, true >(H, Ht, Tf1, Tn1, Tn2, afr, Wp + (size_t)48*64,    b2, w, lg, li, lane);
    __syncthreads();
    layer<128, 64, false, false>(H, Ht, Tf1, Tn1, Tn2, afr, Wp + (size_t)144*64,   b3, w, lg, li, lane);
    __syncthreads();

    // ---- readout: meanmax over nodes + FC (H holds [64 nodes][64 feats])
    float* rm    = (float*)(smem + 32768);   // [4][64]
    float* rx    = rm + 256;                 // [4][64]
    float* smean = rx + 256;                 // [64]
    float* smax  = smean + 64;               // [64]
    const int f = t & 63, q = t >> 6;
    float sum = 0.f, mx = -INFINITY;
    for (int n = q*16; n < q*16 + 16; ++n) {
        float v = bf2f(*(const unsigned short*)((const char*)H + n*256 +
                                                ((f*2) ^ ((n&7)<<4))));
        sum += v; mx = fmaxf(mx, v);
    }
    rm[q*64 + f] = sum; rx[q*64 + f] = mx;
    __syncthreads();
    if (t < 64) {
        smean[t] = (rm[t] + rm[64+t] + rm[128+t] + rm[192+t]) * (1.f/64.f);
        smax[t]  = fmaxf(fmaxf(rx[t], rx[64+t]), fmaxf(rx[128+t], rx[192+t]));
    }
    __syncthreads();
    if (t < 64) {
        float acc = fcb[t];
        for (int f2 = 0; f2 < 64; ++f2)
            acc += smean[f2]*fcw[f2*64 + t] + smax[f2]*fcw[(64 + f2)*64 + t];
        outp[(size_t)g*64 + t] = acc;
    }
}

// ---------------------------------------------------------------------------
extern "C" void kernel_launch(void* const* d_in, const int* in_sizes, int n_in,
                              void* d_out, int out_size, void* d_ws, size_t ws_size,
                              hipStream_t stream)
{
    const float* x   = (const float*)d_in[0];
    const float* ew  = (const float*)d_in[1];
    const float* W1  = (const float*)d_in[2];
    const float* b1  = (const float*)d_in[3];
    const float* W2  = (const float*)d_in[4];
    const float* b2  = (const float*)d_in[5];
    const float* W3  = (const float*)d_in[6];
    const float* b3  = (const float*)d_in[7];
    const float* fcw = (const float*)d_in[8];
    const float* fcb = (const float*)d_in[9];
    const int*   row = (const int*)d_in[10];
    const int*   col = (const int*)d_in[11];

    uint4* Wp = (uint4*)d_ws;   // 192 frags * 64 lanes * 16B = 192KB

    wpack<<<192, 64, 0, stream>>>(W1, W2, W3, Wp);
    fused<<<NG, 256, 0, stream>>>(x, ew, row, col, Wp,
                                  b1, b2, b3, fcw, fcb, (float*)d_out);
}